// Round 1
// baseline (104.274 us; speedup 1.0000x reference)
//
#include <hip/hip_runtime.h>

// Problem constants (from reference): B=32, H=384, W=384, C=2
static constexpr int B_ = 32;
static constexpr int N_ = 384 * 384 * 2;          // 294912 elements per sample
static constexpr int CHUNKS = 36;                 // blocks per sample
static constexpr int EPB = N_ / CHUNKS;           // 8192 elements per block
static constexpr int NBINS = 4096;                // float bits >> 19: 8 exp + 4 mantissa bits
static constexpr int SHIFT = 19;
static constexpr int NEG_POS_RATIO = 3;

// ---------------------------------------------------------------------------
// Kernel 1: per-sample histogram (count + sum) of neg values, pos_loss, mse sum
// ---------------------------------------------------------------------------
__global__ __launch_bounds__(256) void k_hist(const float* __restrict__ y,
                                              const float* __restrict__ o,
                                              const float* __restrict__ w,
                                              unsigned int* __restrict__ hcnt,
                                              float* __restrict__ hsum,
                                              double* __restrict__ pos_acc,
                                              double* __restrict__ mse_acc) {
    __shared__ unsigned int lcnt[NBINS];
    __shared__ float lsum[NBINS];
    const int s = blockIdx.y;
    const int t = threadIdx.x;
    for (int i = t; i < NBINS; i += 256) { lcnt[i] = 0u; lsum[i] = 0.0f; }
    __syncthreads();

    const size_t base = (size_t)s * N_ + (size_t)blockIdx.x * EPB;
    double msed = 0.0, posd = 0.0;

#define PROC(comp)                                                              \
    {                                                                           \
        float d_ = ov.comp - yv.comp;                                           \
        float m_ = d_ * d_;                                                     \
        msed += (double)m_;                                                     \
        if (wv.comp > 0.0f) {                                                   \
            posd += (double)wv.comp * (double)m_;                               \
        } else if (ov.comp > 0.0f && m_ > 0.0f) {                               \
            unsigned int b_ = __float_as_uint(m_) >> SHIFT;                     \
            atomicAdd(&lcnt[b_], 1u);                                           \
            atomicAdd(&lsum[b_], m_);                                           \
        }                                                                       \
    }

#pragma unroll
    for (int it = 0; it < EPB / 1024; ++it) {
        const size_t idx = base + (size_t)(it * 256 + t) * 4;
        const float4 yv = *reinterpret_cast<const float4*>(y + idx);
        const float4 ov = *reinterpret_cast<const float4*>(o + idx);
        const float4 wv = *reinterpret_cast<const float4*>(w + idx);
        PROC(x) PROC(y) PROC(z) PROC(w)
    }
#undef PROC

    __syncthreads();
    // flush LDS histogram to per-sample global histogram
    for (int i = t; i < NBINS; i += 256) {
        unsigned int c = lcnt[i];
        if (c) {
            atomicAdd(&hcnt[s * NBINS + i], c);
            atomicAdd(&hsum[s * NBINS + i], lsum[i]);
        }
    }
    // wave-level reduce of pos / mse, one atomic per wave
#pragma unroll
    for (int off = 32; off > 0; off >>= 1) {
        msed += __shfl_down(msed, off);
        posd += __shfl_down(posd, off);
    }
    if ((t & 63) == 0) {
        atomicAdd(mse_acc, msed);
        atomicAdd(&pos_acc[s], posd);
    }
}

// ---------------------------------------------------------------------------
// Kernel 2: per-sample threshold selection from histogram -> per-sample loss
// ---------------------------------------------------------------------------
__global__ __launch_bounds__(256) void k_select(const unsigned int* __restrict__ hcnt,
                                                const float* __restrict__ hsum,
                                                const double* __restrict__ pos_acc,
                                                const float* __restrict__ tsv,
                                                double* __restrict__ per_sample) {
    const int s = blockIdx.x;
    const int t = threadIdx.x;
    constexpr int BPT = NBINS / 256;  // 16 bins per thread

    __shared__ unsigned int scnt[256], sufc[256];
    __shared__ double ssum[256], sufs[256];
    __shared__ unsigned int total_c;
    __shared__ double total_s;

    const unsigned int* cnt = hcnt + s * NBINS;
    const float* sum = hsum + s * NBINS;
    const int lo = t * BPT;

    unsigned int c = 0; double v = 0.0;
    for (int i = 0; i < BPT; ++i) { c += cnt[lo + i]; v += (double)sum[lo + i]; }
    scnt[t] = c; ssum[t] = v;
    __syncthreads();
    if (t == 0) {
        unsigned int rc = 0; double rs = 0.0;
        for (int i = 255; i >= 0; --i) { sufc[i] = rc; sufs[i] = rs; rc += scnt[i]; rs += ssum[i]; }
        total_c = rc; total_s = rs;
    }
    __syncthreads();

    const float ts = tsv[s];
    long long kk = (long long)floorf(ts) * NEG_POS_RATIO;
    if (kk > N_) kk = N_;
    const int k = (int)kk;

    double neg_loss = 0.0;
    bool have = false;

    if (k <= 0) {
        if (t == 0) { neg_loss = 0.0; have = true; }
    } else if ((unsigned int)k >= total_c) {
        if (t == 0) { neg_loss = total_s; have = true; }
    } else {
        const unsigned int S = sufc[t];
        if (S < (unsigned int)k && (unsigned int)k <= S + scnt[t]) {
            unsigned int c2 = S;
            double acc = sufs[t];
            for (int i = BPT - 1; i >= 0; --i) {
                const unsigned int cb = cnt[lo + i];
                if (c2 + cb < (unsigned int)k) {
                    c2 += cb;
                    acc += (double)sum[lo + i];
                } else {
                    const unsigned int r = (unsigned int)k - c2;  // 1..cb
                    const float sb = sum[lo + i];
                    if (r >= cb) {
                        acc += (double)sb;
                    } else {
                        // uniform-within-bin model: top-r sum = r*(mean + w*(cb-r)/(2cb))
                        const float flo = __uint_as_float((unsigned int)(lo + i) << SHIFT);
                        const float fhi = __uint_as_float((unsigned int)(lo + i + 1) << SHIFT);
                        const double wd = (double)fhi - (double)flo;
                        const double mean = (double)sb / (double)cb;
                        double part = (double)r * (mean + wd * (double)(cb - r) / (2.0 * (double)cb));
                        const double cap = (double)r * (double)fhi;
                        if (part > (double)sb) part = (double)sb;
                        if (part > cap) part = cap;
                        if (part < 0.0) part = 0.0;
                        acc += part;
                    }
                    break;
                }
            }
            neg_loss = acc;
            have = true;
        }
    }

    if (have) {
        const double p = pos_acc[s];
        const double safe = (ts > 0.0f) ? (double)ts : 1.0;
        const double psamp = (p + neg_loss) / safe;  // ALPHA = 1.0
        per_sample[s] = (ts > 0.0f) ? psamp : 0.0;
    }
}

// ---------------------------------------------------------------------------
// Kernel 3: combine per-sample losses + mse mean -> scalar output
// ---------------------------------------------------------------------------
__global__ void k_final(const double* __restrict__ per_sample,
                        const double* __restrict__ mse_acc,
                        float* __restrict__ out) {
    const int t = threadIdx.x;
    double v = (t < B_) ? per_sample[t] : 0.0;
#pragma unroll
    for (int off = 32; off > 0; off >>= 1) v += __shfl_down(v, off);
    if (t == 0) {
        const double train = v / (double)B_;
        const double mean = mse_acc[0] / ((double)B_ * (double)N_);
        out[0] = (float)((train + mean) * 10.0);
    }
}

// ---------------------------------------------------------------------------
extern "C" void kernel_launch(void* const* d_in, const int* in_sizes, int n_in,
                              void* d_out, int out_size, void* d_ws, size_t ws_size,
                              hipStream_t stream) {
    const float* y = (const float*)d_in[0];
    const float* o = (const float*)d_in[1];
    const float* w = (const float*)d_in[2];
    const float* ts = (const float*)d_in[3];

    unsigned char* ws = (unsigned char*)d_ws;
    unsigned int* hcnt = (unsigned int*)ws;                              // 32*4096*4 = 512 KB
    float* hsum = (float*)(ws + (size_t)B_ * NBINS * 4);                 // 512 KB
    double* pos_acc = (double*)(ws + (size_t)B_ * NBINS * 8);            // 32 doubles
    double* mse_acc = pos_acc + B_;                                      // 1 double
    double* per_sample = mse_acc + 1;                                    // 32 doubles

    const size_t zero_bytes = (size_t)B_ * NBINS * 8 + (size_t)(B_ + 1 + B_) * 8;
    hipMemsetAsync(d_ws, 0, zero_bytes, stream);

    dim3 g1(CHUNKS, B_);
    hipLaunchKernelGGL(k_hist, g1, dim3(256), 0, stream, y, o, w, hcnt, hsum, pos_acc, mse_acc);
    hipLaunchKernelGGL(k_select, dim3(B_), dim3(256), 0, stream, hcnt, hsum, pos_acc, ts, per_sample);
    hipLaunchKernelGGL(k_final, dim3(1), dim3(64), 0, stream, per_sample, mse_acc, (float*)d_out);
}

// Round 2
// 55.284 us; speedup vs baseline: 1.8862x; 1.8862x over previous
//
#include <hip/hip_runtime.h>

// Problem constants (from reference): B=32, H=384, W=384, C=2
static constexpr int B_ = 32;
static constexpr int N_ = 384 * 384 * 2;          // 294912 elements per sample
static constexpr int CHUNKS = 36;                 // blocks per sample
static constexpr int EPB = N_ / CHUNKS;           // 8192 elements per block
static constexpr int TPB = 512;                   // threads per block (8 waves)
static constexpr int ROUNDS = EPB / (TPB * 4);    // 4 float4-rounds per thread
static constexpr int NBINS = 2048;                // float bits >> 20: 8 exp + 3 mantissa bits
static constexpr int SHIFT = 20;
static constexpr int NEG_POS_RATIO = 3;
static constexpr int NPART = B_ * CHUNKS;         // 1152 per-block partials

// ---------------------------------------------------------------------------
// Kernel 1: per-sample histogram (count + sum) of neg values; per-block
// pos_loss / mse partials (NO global reduction atomics).
// ---------------------------------------------------------------------------
__global__ __launch_bounds__(TPB, 8) void k_hist(const float* __restrict__ y,
                                                 const float* __restrict__ o,
                                                 const float* __restrict__ w,
                                                 unsigned int* __restrict__ hcnt,
                                                 float* __restrict__ hsum,
                                                 double* __restrict__ pos_part,
                                                 double* __restrict__ mse_part) {
    __shared__ unsigned int lcnt[NBINS];
    __shared__ float lsum[NBINS];
    __shared__ double red[2 * (TPB / 64)];
    const int s = blockIdx.y;
    const int t = threadIdx.x;
    for (int i = t; i < NBINS; i += TPB) { lcnt[i] = 0u; lsum[i] = 0.0f; }
    __syncthreads();

    const size_t base = (size_t)s * N_ + (size_t)blockIdx.x * EPB;
    double msed = 0.0, posd = 0.0;

#define PROC(comp)                                                              \
    {                                                                           \
        float d_ = ov.comp - yv.comp;                                           \
        float m_ = d_ * d_;                                                     \
        msed += (double)m_;                                                     \
        if (wv.comp > 0.0f) {                                                   \
            posd += (double)wv.comp * (double)m_;                               \
        } else if (ov.comp > 0.0f && m_ > 0.0f) {                               \
            unsigned int b_ = __float_as_uint(m_) >> SHIFT;                     \
            atomicAdd(&lcnt[b_], 1u);                                           \
            atomicAdd(&lsum[b_], m_);                                           \
        }                                                                       \
    }

    // register double-buffer: issue next round's loads before processing current
    size_t idx = base + (size_t)t * 4;
    float4 yv = *reinterpret_cast<const float4*>(y + idx);
    float4 ov = *reinterpret_cast<const float4*>(o + idx);
    float4 wv = *reinterpret_cast<const float4*>(w + idx);
#pragma unroll
    for (int it = 0; it < ROUNDS; ++it) {
        float4 yn, on, wn;
        if (it + 1 < ROUNDS) {
            const size_t nidx = base + (size_t)((it + 1) * TPB + t) * 4;
            yn = *reinterpret_cast<const float4*>(y + nidx);
            on = *reinterpret_cast<const float4*>(o + nidx);
            wn = *reinterpret_cast<const float4*>(w + nidx);
        }
        PROC(x) PROC(y) PROC(z) PROC(w)
        if (it + 1 < ROUNDS) { yv = yn; ov = on; wv = wn; }
    }
#undef PROC

    // wave-level reduce of pos / mse -> LDS -> single plain store per block
#pragma unroll
    for (int off = 32; off > 0; off >>= 1) {
        msed += __shfl_down(msed, off);
        posd += __shfl_down(posd, off);
    }
    if ((t & 63) == 0) {
        const int wid = t >> 6;
        red[wid] = msed;
        red[(TPB / 64) + wid] = posd;
    }
    __syncthreads();

    // flush LDS histogram to per-sample global histogram
    for (int i = t; i < NBINS; i += TPB) {
        const unsigned int c = lcnt[i];
        if (c) {
            atomicAdd(&hcnt[s * NBINS + i], c);
            atomicAdd(&hsum[s * NBINS + i], lsum[i]);
        }
    }
    if (t == 0) {
        double m = 0.0, p = 0.0;
#pragma unroll
        for (int i = 0; i < TPB / 64; ++i) { m += red[i]; p += red[(TPB / 64) + i]; }
        const int blk = s * CHUNKS + blockIdx.x;
        mse_part[blk] = m;
        pos_part[blk] = p;
    }
}

// ---------------------------------------------------------------------------
// Kernel 2: per-sample threshold selection from histogram -> per-sample loss
// ---------------------------------------------------------------------------
__global__ __launch_bounds__(256) void k_select(const unsigned int* __restrict__ hcnt,
                                                const float* __restrict__ hsum,
                                                const double* __restrict__ pos_part,
                                                const float* __restrict__ tsv,
                                                double* __restrict__ per_sample) {
    const int s = blockIdx.x;
    const int t = threadIdx.x;
    constexpr int BPT = NBINS / 256;  // 8 bins per thread

    __shared__ unsigned int scnt[256], sufc[256];
    __shared__ double ssum[256], sufs[256];
    __shared__ unsigned int total_c;
    __shared__ double total_s;
    __shared__ double spos;

    // sum this sample's 36 per-block pos partials (lanes 0..35 of wave 0)
    {
        double p = (t < CHUNKS) ? pos_part[s * CHUNKS + t] : 0.0;
        if (t < 64) {
#pragma unroll
            for (int off = 32; off > 0; off >>= 1) p += __shfl_down(p, off);
            if (t == 0) spos = p;
        }
    }

    const unsigned int* cnt = hcnt + s * NBINS;
    const float* sum = hsum + s * NBINS;
    const int lo = t * BPT;

    unsigned int c = 0; double v = 0.0;
    for (int i = 0; i < BPT; ++i) { c += cnt[lo + i]; v += (double)sum[lo + i]; }
    scnt[t] = c; ssum[t] = v;
    __syncthreads();
    if (t == 0) {
        unsigned int rc = 0; double rs = 0.0;
        for (int i = 255; i >= 0; --i) { sufc[i] = rc; sufs[i] = rs; rc += scnt[i]; rs += ssum[i]; }
        total_c = rc; total_s = rs;
    }
    __syncthreads();

    const float ts = tsv[s];
    long long kk = (long long)floorf(ts) * NEG_POS_RATIO;
    if (kk > N_) kk = N_;
    const int k = (int)kk;

    double neg_loss = 0.0;
    bool have = false;

    if (k <= 0) {
        if (t == 0) { neg_loss = 0.0; have = true; }
    } else if ((unsigned int)k >= total_c) {
        if (t == 0) { neg_loss = total_s; have = true; }
    } else {
        const unsigned int S = sufc[t];
        if (S < (unsigned int)k && (unsigned int)k <= S + scnt[t]) {
            unsigned int c2 = S;
            double acc = sufs[t];
            for (int i = BPT - 1; i >= 0; --i) {
                const unsigned int cb = cnt[lo + i];
                if (c2 + cb < (unsigned int)k) {
                    c2 += cb;
                    acc += (double)sum[lo + i];
                } else {
                    const unsigned int r = (unsigned int)k - c2;  // 1..cb
                    const float sb = sum[lo + i];
                    if (r >= cb) {
                        acc += (double)sb;
                    } else {
                        // uniform-within-bin model: top-r sum = r*(mean + w*(cb-r)/(2cb))
                        const float flo = __uint_as_float((unsigned int)(lo + i) << SHIFT);
                        const float fhi = __uint_as_float((unsigned int)(lo + i + 1) << SHIFT);
                        const double wd = (double)fhi - (double)flo;
                        const double mean = (double)sb / (double)cb;
                        double part = (double)r * (mean + wd * (double)(cb - r) / (2.0 * (double)cb));
                        const double cap = (double)r * (double)fhi;
                        if (part > (double)sb) part = (double)sb;
                        if (part > cap) part = cap;
                        if (part < 0.0) part = 0.0;
                        acc += part;
                    }
                    break;
                }
            }
            neg_loss = acc;
            have = true;
        }
    }

    if (have) {
        const double p = spos;
        const double safe = (ts > 0.0f) ? (double)ts : 1.0;
        const double psamp = (p + neg_loss) / safe;  // ALPHA = 1.0
        per_sample[s] = (ts > 0.0f) ? psamp : 0.0;
    }
}

// ---------------------------------------------------------------------------
// Kernel 3: combine per-sample losses + mse partials -> scalar output
// ---------------------------------------------------------------------------
__global__ __launch_bounds__(256) void k_final(const double* __restrict__ per_sample,
                                               const double* __restrict__ mse_part,
                                               float* __restrict__ out) {
    const int t = threadIdx.x;
    __shared__ double sm[4], sv[4];
    double m = 0.0;
    for (int i = t; i < NPART; i += 256) m += mse_part[i];
    double v = (t < B_) ? per_sample[t] : 0.0;
#pragma unroll
    for (int off = 32; off > 0; off >>= 1) {
        m += __shfl_down(m, off);
        v += __shfl_down(v, off);
    }
    if ((t & 63) == 0) { sm[t >> 6] = m; sv[t >> 6] = v; }
    __syncthreads();
    if (t == 0) {
        double mt = 0.0, vt = 0.0;
#pragma unroll
        for (int i = 0; i < 4; ++i) { mt += sm[i]; vt += sv[i]; }
        const double train = vt / (double)B_;
        const double mean = mt / ((double)B_ * (double)N_);
        out[0] = (float)((train + mean) * 10.0);
    }
}

// ---------------------------------------------------------------------------
extern "C" void kernel_launch(void* const* d_in, const int* in_sizes, int n_in,
                              void* d_out, int out_size, void* d_ws, size_t ws_size,
                              hipStream_t stream) {
    const float* y = (const float*)d_in[0];
    const float* o = (const float*)d_in[1];
    const float* w = (const float*)d_in[2];
    const float* ts = (const float*)d_in[3];

    unsigned char* ws = (unsigned char*)d_ws;
    unsigned int* hcnt = (unsigned int*)ws;                              // 32*2048*4 = 256 KB
    float* hsum = (float*)(ws + (size_t)B_ * NBINS * 4);                 // 256 KB
    double* pos_part = (double*)(ws + (size_t)B_ * NBINS * 8);           // 1152 doubles
    double* mse_part = pos_part + NPART;                                 // 1152 doubles
    double* per_sample = mse_part + NPART;                               // 32 doubles

    // only the histograms need zeroing; partials are written unconditionally
    hipMemsetAsync(d_ws, 0, (size_t)B_ * NBINS * 8, stream);

    dim3 g1(CHUNKS, B_);
    hipLaunchKernelGGL(k_hist, g1, dim3(TPB), 0, stream, y, o, w, hcnt, hsum, pos_part, mse_part);
    hipLaunchKernelGGL(k_select, dim3(B_), dim3(256), 0, stream, hcnt, hsum, pos_part, ts, per_sample);
    hipLaunchKernelGGL(k_final, dim3(1), dim3(256), 0, stream, per_sample, mse_part, (float*)d_out);
}